// Round 13
// baseline (562.774 us; speedup 1.0000x reference)
//
#include <hip/hip_runtime.h>

namespace {

typedef float f32x4 __attribute__((ext_vector_type(4)));

constexpr int H = 17, W = 17, NC = H * W;   // 289 cells
constexpr int SW = 20, SH = 19;             // LDS tile stride, 1-wide zero halo
constexpr int NT = 320;                     // 5 waves; critical SIMD carries 2 (TLP)

#define PIN(x) asm volatile("" : "+v"(x))

__device__ __forceinline__ float clip10(float v) {
    return fminf(fmaxf(v, -10.f), 10.f);
}
__device__ __forceinline__ float max3f(float a, float b, float c) {
    return fmaxf(fmaxf(a, b), c);   // v_max3_f32
}

__device__ __forceinline__ float scent_at(int hy, int wx, const float* __restrict__ food) {
    const float SK[5][5] = {
        {0.f,   .125f, .25f, .125f, 0.f},
        {.125f, .25f,  .5f,  .25f,  .125f},
        {.25f,  .5f,   1.f,  .5f,   .25f},
        {.125f, .25f,  .5f,  .25f,  .125f},
        {0.f,   .125f, .25f, .125f, 0.f}};
    float sc = 0.f;
    #pragma unroll
    for (int dy = -2; dy <= 2; ++dy) {
        #pragma unroll
        for (int dx = -2; dx <= 2; ++dx) {
            const float k = SK[dy + 2][dx + 2];
            if (k != 0.f) {
                const int yy = hy + dy, xx = wx + dx;
                if (yy >= 0 && yy < H && xx >= 0 && xx < W)
                    sc = fmaf(k, food[yy * W + xx], sc);
            }
        }
    }
    return sc;
}

// 9 taps from a padded SoA float array
#define LOAD9(ARR, IDX, T)                                                        \
    const float T##00 = ARR[(IDX)-SW-1], T##01 = ARR[(IDX)-SW], T##02 = ARR[(IDX)-SW+1], \
                T##10 = ARR[(IDX)-1],    T##11 = ARR[(IDX)],    T##12 = ARR[(IDX)+1],    \
                T##20 = ARR[(IDX)+SW-1], T##21 = ARR[(IDX)+SW], T##22 = ARR[(IDX)+SW+1];

// prep: pack 49 pre-scaled weight quads into d_ws.
// quad layout per unit o: q[3o]   = {w3[o,0], w3[o,1], w3[o,2], w3[o,4]/8}
//                         q[3o+1] = {w3[o,5]/8, w3[o,6]/8, w3[o,8]/8, w3[o,9]/8}
//                         q[3o+2] = {w3[o,10]/8, w4[0,o], w4[1,o], w4[2,o]}
// q[48] = {b4[0], b4[1], b4[2], 0}
__global__ void prep_kernel(const float* __restrict__ w3,
                            const float* __restrict__ w4,
                            const float* __restrict__ b4,
                            float* __restrict__ ws)
{
    const int o = (int)threadIdx.x;
    f32x4* q = (f32x4*)ws;
    if (o < 16) {
        q[3*o]   = (f32x4){w3[o*12+0], w3[o*12+1], w3[o*12+2], w3[o*12+4]*0.125f};
        q[3*o+1] = (f32x4){w3[o*12+5]*0.125f, w3[o*12+6]*0.125f,
                           w3[o*12+8]*0.125f, w3[o*12+9]*0.125f};
        q[3*o+2] = (f32x4){w3[o*12+10]*0.125f, w4[o], w4[16+o], w4[32+o]};
    } else if (o == 16) {
        q[48] = (f32x4){b4[0], b4[1], b4[2], 0.f};
    }
}

__launch_bounds__(NT, 2)
__global__ void ca_kernel(const float* __restrict__ cell_in,
                          const float* __restrict__ food,
                          const float* __restrict__ w3,
                          const float* __restrict__ b3,
                          const int* __restrict__ steps_p,
                          const float* __restrict__ wq,
                          float* __restrict__ out)
{
    __shared__ float c0s[SH * SW];
    __shared__ float c1s[SH * SW];
    __shared__ float c2s[SH * SW];
    __shared__ float scs[SH * SW];   // scent (pre-loop only)
    __shared__ float xb[SH * SW];    // x[0] exchange for post-alive maxpool
    __shared__ float red[NT];

    const int tid = (int)threadIdx.x;
    const int steps = steps_p[0];
    const bool act = tid < NC;

    // Opaque per-lane zero: compiler cannot prove the weight base wave-uniform,
    // so weight loads become global_load_dwordx4 (VMEM/vmcnt, batched) instead
    // of s_load (scalar/lgkmcnt, serialized against LDS waits).
    unsigned vzero;
    asm("v_mov_b32 %0, 0" : "=v"(vzero));
    const f32x4* __restrict__ qv = (const f32x4*)((const char*)wq + vzero);

    // zero LDS (halo zeros are decision-equivalent to -inf pad: threshold 0.1 > 0)
    for (int i = tid; i < SH * SW; i += NT) {
        c0s[i] = 0.f; c1s[i] = 0.f; c2s[i] = 0.f; scs[i] = 0.f; xb[i] = 0.f;
    }
    __syncthreads();

    const int hy = act ? tid / W : 0;
    const int wx = act ? tid % W : 0;
    const int idx = (hy + 1) * SW + wx + 1;

    // per-cell state centers live in registers across the whole loop
    float cur0 = 0.f, cur1 = 0.f, cur2 = 0.f, sc = 0.f;
    if (act) {
        cur0 = cell_in[tid];
        cur1 = cell_in[NC + tid];
        cur2 = cell_in[2 * NC + tid];
        sc   = scent_at(hy, wx, food);
        c0s[idx] = cur0;
        c1s[idx] = cur1;
        c2s[idx] = cur2;
        scs[idx] = sc;
    }
    __syncthreads();

    // ---- fold loop-invariant scent perception into per-cell bias be[] ----
    float be[16];
    {
        LOAD9(scs, idx, s)
        const float dxs = ((s02-s00) + 2.f*(s12-s10) + (s22-s20)) * 0.125f;
        const float dys = ((s20+2.f*s21+s22) - (s00+2.f*s01+s02)) * 0.125f;
        #pragma unroll
        for (int o = 0; o < 16; ++o)
            be[o] = fmaf(w3[o*12+3], s11, fmaf(w3[o*12+7], dxs,
                    fmaf(w3[o*12+11], dys, b3[o])));
    }
    #pragma unroll
    for (int o = 0; o < 16; ++o) PIN(be[o]);

    // loop-invariant b4 quad, hoisted and pinned
    const f32x4 bq = qv[48];
    float b40 = bq.x, b41 = bq.y, b42 = bq.z;
    PIN(b40); PIN(b41); PIN(b42);

    // ---- main loop: 2 barriers/step; weights stream per step as 48 uniform
    //      b128 VMEM loads (L1 broadcast, vmcnt-batched by the compiler) ----
    for (int s = 0; s < steps; ++s) {
        float n0 = 0.f, n1 = 0.f, n2 = 0.f;
        bool pre = false;
        if (act) {
            LOAD9(c0s, idx, p) LOAD9(c1s, idx, a) LOAD9(c2s, idx, r)
            const float y0 = cur0, y1 = cur1, y2 = cur2;
            const float y3 = (p02-p00) + 2.f*(p12-p10) + (p22-p20);
            const float y4 = (a02-a00) + 2.f*(a12-a10) + (a22-a20);
            const float y5 = (r02-r00) + 2.f*(r12-r10) + (r22-r20);
            const float y6 = (p20+2.f*p21+p22) - (p00+2.f*p01+p02);
            const float y7 = (a20+2.f*a21+a22) - (a00+2.f*a01+a02);
            const float y8 = (r20+2.f*r21+r22) - (r00+2.f*r01+r02);
            pre = max3f(max3f(p00,p01,p02), max3f(p10,cur0,p12),
                        max3f(p20,p21,p22)) > 0.1f;

            float d0 = b40, d1 = b41, d2 = b42;
            #pragma unroll
            for (int o = 0; o < 16; ++o) {
                const f32x4 qa = qv[3*o], qb = qv[3*o+1], qc = qv[3*o+2];
                float h = be[o];
                h = fmaf(qa.x, y0, h); h = fmaf(qa.y, y1, h);
                h = fmaf(qa.z, y2, h); h = fmaf(qa.w, y3, h);
                h = fmaf(qb.x, y4, h); h = fmaf(qb.y, y5, h);
                h = fmaf(qb.z, y6, h); h = fmaf(qb.w, y7, h);
                h = fmaf(qc.x, y8, h);
                h = fmaxf(h, 0.f);
                d0 = fmaf(qc.y, h, d0);
                d1 = fmaf(qc.z, h, d1);
                d2 = fmaf(qc.w, h, d2);
            }
            n0 = y0 + d0; n1 = y1 + d1; n2 = y2 + d2;
            xb[idx] = n0;
        }
        __syncthreads();
        if (act) {
            // post-alive maxpool; center tap n0 from register (8 LDS taps)
            const float x00 = xb[idx-SW-1], x01 = xb[idx-SW], x02 = xb[idx-SW+1];
            const float x10 = xb[idx-1],                      x12 = xb[idx+1];
            const float x20 = xb[idx+SW-1], x21 = xb[idx+SW], x22 = xb[idx+SW+1];
            const float mx2 = max3f(max3f(x00,x01,x02), max3f(x10,n0,x12),
                                    max3f(x20,x21,x22));
            const float m = (pre && (mx2 > 0.1f)) ? 1.f : 0.f;
            cur0 = clip10(n0 * m);
            cur1 = clip10(n1 * m);
            cur2 = clip10(n2 * m);
            c0s[idx] = cur0;
            c1s[idx] = cur1;
            c2s[idx] = cur2;
        }
        __syncthreads();
    }

    // ---- outputs: cell (4*289) | food (289) | living_count (1) ----
    if (act) {
        out[tid]          = cur0;
        out[NC + tid]     = cur1;
        out[2 * NC + tid] = cur2;
        out[3 * NC + tid] = clip10(sc);
        out[4 * NC + tid] = food[tid];
        red[tid] = cur0;
    } else {
        red[tid] = 0.f;
    }
    __syncthreads();
    if (tid < 64) {
        float s2 = red[tid] + red[tid + 64] + red[tid + 128]
                 + red[tid + 192] + red[tid + 256];
        #pragma unroll
        for (int off = 32; off > 0; off >>= 1)
            s2 += __shfl_down(s2, off, 64);
        if (tid == 0) out[5 * NC] = s2;
    }
}

}  // namespace

extern "C" void kernel_launch(void* const* d_in, const int* in_sizes, int n_in,
                              void* d_out, int out_size, void* d_ws, size_t ws_size,
                              hipStream_t stream) {
    const float* cell = (const float*)d_in[0];
    const float* food = (const float*)d_in[1];
    const float* w3   = (const float*)d_in[2];
    const float* b3   = (const float*)d_in[3];
    const float* w4   = (const float*)d_in[4];
    const float* b4   = (const float*)d_in[5];
    const int*   st   = (const int*)d_in[6];
    float* out = (float*)d_out;
    float* ws  = (float*)d_ws;
    prep_kernel<<<1, 64, 0, stream>>>(w3, w4, b4, ws);
    ca_kernel<<<1, NT, 0, stream>>>(cell, food, w3, b3, st, ws, out);
}